// Round 6
// baseline (90.747 us; speedup 1.0000x reference)
//
#include <hip/hip_runtime.h>

// Fully-fused LSA, R6: 2-tile sliding-window blocks. R5 (kernel ~34us) was
// stall-bound: 3 lock-step barriers/tile with phase-locked resident blocks,
// Wv f32 re-loaded per 4-row tile (33 MB), y-halo rows fetched twice. R6:
// each block does 8 output rows as two 4-row halves over an 8-slot halo ring:
//   P0: loadA (halo rows y0-2..y0+5 -> slots 0..7, verbatim R5 map) + attn(2 halves)
//   P1: ISSUE loadB (rows y0+6..y0+9) + Wv f32 to regs, then stencilA + packA
//       (loads complete under the 5.5us stencil -> latency fully hidden)
//   P2: drainB -> slots 0..3 ; Wv -> bf16 -> wvs
//   P3: gemmA + epilogueA ; stencilB (ring slot = (4+yi+dy)&7, else verbatim)
//   P4: packB   P5: gemmB + epilogueB
// Wv converted once per 2 tiles; halo fetch 12 rows per 8 output rows (was 16).
// All inner loops / LDS layouts byte-identical to R5 (verified, absmax 0.125).
// B=4, C=128, H=64, W=128, L=25. LDS 117.2 KB -> 1 block/CU, 8 waves.

namespace {
constexpr int Bn = 4, Cn = 128, Hn = 64, Wn = 128, Ln = 25;
constexpr int HWn = Hn * Wn;  // 8192

constexpr int TX = 16;           // x-tile; block covers 8 output rows (2 halves of 4)
constexpr int HX = 24;           // halo cols (x0-4 .. x0+19)
constexpr int RS = 136;          // hs row stride in halves (272B, 16B-aligned)
constexpr int SVS = 136;         // sv row stride in halves
constexpr int WVS = 136;         // wvs row stride in halves
constexpr int NT = 512;          // threads/block

typedef __attribute__((ext_vector_type(8))) short short8;
typedef __attribute__((ext_vector_type(4))) float f32x4;

__device__ inline unsigned short f2bf(float f) {
    unsigned u = __float_as_uint(f);
    return (unsigned short)((u + 0x7fffu + ((u >> 16) & 1u)) >> 16);  // RNE
}

__global__ __launch_bounds__(NT, 2) void lsa_fused(
    const float* __restrict__ attn, const float* __restrict__ fmap,
    const float* __restrict__ Wv, const float* __restrict__ gamma,
    float* __restrict__ out)
{
    __shared__ alignas(16) unsigned short hs[8 * HX * RS];    // 52.2 KB halo ring
    __shared__ alignas(16) unsigned short sv[64 * SVS];       // 17.4 KB
    __shared__ alignas(16) unsigned short wvs[128 * WVS];     // 34.8 KB
    __shared__ alignas(16) float at_s[2 * 64 * Ln];           // 12.8 KB

    const int tid = threadIdx.x;

    // XCD swizzle for 256 blocks: each XCD gets 32 consecutive logical blocks
    // = one 32-row band of one batch (2 MB fmap slice < 4 MB L2). Bijective.
    const unsigned bid = blockIdx.x;                 // 0..255
    const unsigned logical = (bid & 7u) * 32u + (bid >> 3);
    const int bx  = logical & 7;        // 8 x-tiles
    const int byb = (logical >> 3) & 7; // 8 y-blocks (8 rows each)
    const int b   = logical >> 6;       // 4 batches
    const int x0 = bx * TX;
    const int y0 = byb * 8;

    // ---- P0a: issue loadA into regs (12 float4; halo rows y0-2..y0+5) ----
    // item i -> (k = gx-quad 0..5, cp = channel-pair 0..63, dy = 0..7). Quads
    // fully in-range or fully clamped (verbatim R5 map).
    float4 va[6], vb[6];
#pragma unroll
    for (int t = 0; t < 6; ++t) {
        const int i = tid + t * NT;            // 3072 items exactly
        const int k = i % 6;
        const int r = i / 6;
        const int cp = r & 63;
        const int dy = r >> 6;
        const int ry = min(max(y0 + dy - 2, 0), Hn - 1);
        const int gxb = x0 - 4 + 4 * k;
        const size_t rowb = ((size_t)(b * Cn + 2 * cp)) * HWn + (size_t)ry * Wn;
        if (gxb < 0) {                       // only bx==0, k==0: replicate col 0
            const float s0 = fmap[rowb], s1 = fmap[rowb + HWn];
            va[t].x = va[t].y = va[t].z = va[t].w = s0;
            vb[t].x = vb[t].y = vb[t].z = vb[t].w = s1;
        } else if (gxb > Wn - 4) {           // only bx==7, k==5: replicate col W-1
            const float s0 = fmap[rowb + Wn - 1], s1 = fmap[rowb + HWn + Wn - 1];
            va[t].x = va[t].y = va[t].z = va[t].w = s0;
            vb[t].x = vb[t].y = vb[t].z = vb[t].w = s1;
        } else {
            va[t] = *(const float4*)&fmap[rowb + gxb];
            vb[t] = *(const float4*)&fmap[rowb + HWn + gxb];
        }
    }
    // attn for both halves: 2*64 px * 25 = 3200 floats = 800 float4, linear.
    // at_s[h*1600 + yi*400 + (xi*25+l)] == attn[ab + h*12800 + yi*3200 + j].
    const size_t ab = ((size_t)b * HWn + (size_t)y0 * Wn + x0) * Ln;
    float4 at0, at1;
    {
        const int i4 = tid;                    // always < 800
        const int h = i4 / 400, rem = i4 - h * 400;
        const int yia = rem / 100, j4 = (rem - yia * 100) * 4;
        at0 = *(const float4*)&attn[ab + (size_t)h * 12800 + (size_t)yia * 3200 + j4];
    }
    if (tid < 288) {
        const int i4 = tid + 512;              // 512..799
        const int h = i4 / 400, rem = i4 - h * 400;
        const int yia = rem / 100, j4 = (rem - yia * 100) * 4;
        at1 = *(const float4*)&attn[ab + (size_t)h * 12800 + (size_t)yia * 3200 + j4];
    }

    // ---- P0b: drain loadA to hs slots 0..7 (verbatim R5) + at_s ----
#pragma unroll
    for (int t = 0; t < 6; ++t) {
        const int i = tid + t * NT;
        const int k = i % 6;
        const int r = i / 6;
        const int cp = r & 63;
        const int dy = r >> 6;
        unsigned short* hbase = &hs[(dy * HX + 4 * k) * RS + 2 * cp];
        *(unsigned*)&hbase[0 * RS] = (unsigned)f2bf(va[t].x) | ((unsigned)f2bf(vb[t].x) << 16);
        *(unsigned*)&hbase[1 * RS] = (unsigned)f2bf(va[t].y) | ((unsigned)f2bf(vb[t].y) << 16);
        *(unsigned*)&hbase[2 * RS] = (unsigned)f2bf(va[t].z) | ((unsigned)f2bf(vb[t].z) << 16);
        *(unsigned*)&hbase[3 * RS] = (unsigned)f2bf(va[t].w) | ((unsigned)f2bf(vb[t].w) << 16);
    }
    *(float4*)&at_s[tid * 4] = at0;
    if (tid < 288) *(float4*)&at_s[(tid + 512) * 4] = at1;
    __syncthreads();  // B1

    // ---- P1: issue Wv f32 + loadB (rows y0+6..y0+9) to regs, then stencilA ----
    float4 wq[8];
#pragma unroll
    for (int t = 0; t < 8; ++t)
        wq[t] = *(const float4*)&Wv[(size_t)(tid + t * NT) * 4];

    float4 va2[3], vb2[3];
#pragma unroll
    for (int t = 0; t < 3; ++t) {
        const int j = tid + t * NT;            // 1536 items: (k, cp, dyp 0..3)
        const int k = j % 6;
        const int r = j / 6;
        const int cp = r & 63;
        const int dyp = r >> 6;
        const int ry = min(y0 + 6 + dyp, Hn - 1);   // lower clamp impossible
        const int gxb = x0 - 4 + 4 * k;
        const size_t rowb = ((size_t)(b * Cn + 2 * cp)) * HWn + (size_t)ry * Wn;
        if (gxb < 0) {
            const float s0 = fmap[rowb], s1 = fmap[rowb + HWn];
            va2[t].x = va2[t].y = va2[t].z = va2[t].w = s0;
            vb2[t].x = vb2[t].y = vb2[t].z = vb2[t].w = s1;
        } else if (gxb > Wn - 4) {
            const float s0 = fmap[rowb + Wn - 1], s1 = fmap[rowb + HWn + Wn - 1];
            va2[t].x = va2[t].y = va2[t].z = va2[t].w = s0;
            vb2[t].x = vb2[t].y = vb2[t].z = vb2[t].w = s1;
        } else {
            va2[t] = *(const float4*)&fmap[rowb + gxb];
            vb2[t] = *(const float4*)&fmap[rowb + HWn + gxb];
        }
    }

    // stencilA (verbatim R5): xi = tid&15, kq = (tid>>4)&7, yi = tid>>7
    const int xi = tid & 15, kq = (tid >> 4) & 7, yi = tid >> 7;
    const int p = yi * 16 + xi;
    float acc[16];
#pragma unroll
    for (int j = 0; j < 16; ++j) acc[j] = 0.f;

#pragma unroll
    for (int l = 0; l < Ln; ++l) {
        const int dy = l / 5, dx = l % 5;
        const float a = at_s[p * Ln + l];
        const unsigned short* row = &hs[((yi + dy) * HX + (2 + xi + dx)) * RS + kq * 16];
#pragma unroll
        for (int q = 0; q < 2; ++q) {
            uint4 u = *(const uint4*)&row[q * 8];
            const unsigned w[4] = {u.x, u.y, u.z, u.w};
#pragma unroll
            for (int e = 0; e < 4; ++e) {
                acc[q * 8 + 2 * e + 0] += a * __uint_as_float(w[e] << 16);
                acc[q * 8 + 2 * e + 1] += a * __uint_as_float(w[e] & 0xffff0000u);
            }
        }
    }
    // packA -> sv (verbatim R5)
    {
        unsigned short* dst = &sv[p * SVS + kq * 16];
#pragma unroll
        for (int q = 0; q < 2; ++q) {
            unsigned pk[4];
#pragma unroll
            for (int e = 0; e < 4; ++e)
                pk[e] = (unsigned)f2bf(acc[q * 8 + 2 * e]) |
                        ((unsigned)f2bf(acc[q * 8 + 2 * e + 1]) << 16);
            uint4 v; v.x = pk[0]; v.y = pk[1]; v.z = pk[2]; v.w = pk[3];
            *(uint4*)&dst[q * 8] = v;
        }
    }
    __syncthreads();  // B2: stencilA hs reads done -> slots 0..3 reusable; svA staged

    // ---- P2: drainB -> hs slots 0..3 ; Wv -> bf16 -> wvs ----
#pragma unroll
    for (int t = 0; t < 3; ++t) {
        const int j = tid + t * NT;
        const int k = j % 6;
        const int r = j / 6;
        const int cp = r & 63;
        const int dyp = r >> 6;                // slot = (8+dyp)&7 = dyp
        unsigned short* hbase = &hs[(dyp * HX + 4 * k) * RS + 2 * cp];
        *(unsigned*)&hbase[0 * RS] = (unsigned)f2bf(va2[t].x) | ((unsigned)f2bf(vb2[t].x) << 16);
        *(unsigned*)&hbase[1 * RS] = (unsigned)f2bf(va2[t].y) | ((unsigned)f2bf(vb2[t].y) << 16);
        *(unsigned*)&hbase[2 * RS] = (unsigned)f2bf(va2[t].z) | ((unsigned)f2bf(vb2[t].z) << 16);
        *(unsigned*)&hbase[3 * RS] = (unsigned)f2bf(va2[t].w) | ((unsigned)f2bf(vb2[t].w) << 16);
    }
#pragma unroll
    for (int t = 0; t < 8; ++t) {
        const int i4 = tid + t * NT;           // float4 index within Wv, 0..4095
        const int r = i4 >> 5;                 // row (32 float4 per 128-col row)
        const int c = (i4 & 31) * 4;
        uint2 v;
        v.x = (unsigned)f2bf(wq[t].x) | ((unsigned)f2bf(wq[t].y) << 16);
        v.y = (unsigned)f2bf(wq[t].z) | ((unsigned)f2bf(wq[t].w) << 16);
        *(uint2*)&wvs[r * WVS + c] = v;
    }
    __syncthreads();  // B3

    // ---- P3: gemmA + epilogueA (verbatim R5 mapping), then stencilB ----
    const int wave = tid >> 6, lane = tid & 63;
    const int m16 = lane & 15, q = lane >> 4;
    const int wrow = wave >> 1;            // pixel row within half
    const int mhalf = wave & 1;            // 64-channel half
    const float g = gamma[0];

    {
        const int n = (y0 + wrow) * Wn + x0 + m16;
        short8 bfrag[4];
        const unsigned short* srow = &sv[(wrow * 16 + m16) * SVS + q * 8];
#pragma unroll
        for (int kk = 0; kk < 4; ++kk) bfrag[kk] = *(const short8*)(srow + kk * 32);
        f32x4 accv[4];
#pragma unroll
        for (int t = 0; t < 4; ++t) { f32x4 z = {0.f, 0.f, 0.f, 0.f}; accv[t] = z; }
#pragma unroll
        for (int t = 0; t < 4; ++t) {
            const int mg = mhalf * 4 + t;
            const unsigned short* arow = &wvs[(mg * 16 + m16) * WVS + q * 8];
#pragma unroll
            for (int kk = 0; kk < 4; ++kk) {
                short8 af = *(const short8*)(arow + kk * 32);
                accv[t] = __builtin_amdgcn_mfma_f32_16x16x32_bf16(af, bfrag[kk], accv[t], 0, 0, 0);
            }
        }
#pragma unroll
        for (int t = 0; t < 4; ++t) {
            const int mg = mhalf * 4 + t;
#pragma unroll
            for (int r = 0; r < 4; ++r) {
                const int c = mg * 16 + q * 4 + r;
                const size_t idx = ((size_t)(b * Cn + c)) * HWn + n;
                out[idx] = fmap[idx] + g * accv[t][r];
            }
        }
    }

    // stencilB: ring slot = (4 + yi + dy) & 7; attn from half-1 region.
#pragma unroll
    for (int j = 0; j < 16; ++j) acc[j] = 0.f;
#pragma unroll
    for (int l = 0; l < Ln; ++l) {
        const int dy = l / 5, dx = l % 5;
        const float a = at_s[1600 + p * Ln + l];
        const unsigned short* row = &hs[((((4 + yi + dy) & 7)) * HX + (2 + xi + dx)) * RS + kq * 16];
#pragma unroll
        for (int q2 = 0; q2 < 2; ++q2) {
            uint4 u = *(const uint4*)&row[q2 * 8];
            const unsigned w[4] = {u.x, u.y, u.z, u.w};
#pragma unroll
            for (int e = 0; e < 4; ++e) {
                acc[q2 * 8 + 2 * e + 0] += a * __uint_as_float(w[e] << 16);
                acc[q2 * 8 + 2 * e + 1] += a * __uint_as_float(w[e] & 0xffff0000u);
            }
        }
    }
    __syncthreads();  // B4: gemmA sv reads done -> sv reusable

    // ---- P4: packB -> sv ----
    {
        unsigned short* dst = &sv[p * SVS + kq * 16];
#pragma unroll
        for (int q2 = 0; q2 < 2; ++q2) {
            unsigned pk[4];
#pragma unroll
            for (int e = 0; e < 4; ++e)
                pk[e] = (unsigned)f2bf(acc[q2 * 8 + 2 * e]) |
                        ((unsigned)f2bf(acc[q2 * 8 + 2 * e + 1]) << 16);
            uint4 v; v.x = pk[0]; v.y = pk[1]; v.z = pk[2]; v.w = pk[3];
            *(uint4*)&dst[q2 * 8] = v;
        }
    }
    __syncthreads();  // B5

    // ---- P5: gemmB + epilogueB (rows y0+4..y0+7) ----
    {
        const int n = (y0 + 4 + wrow) * Wn + x0 + m16;
        short8 bfrag[4];
        const unsigned short* srow = &sv[(wrow * 16 + m16) * SVS + q * 8];
#pragma unroll
        for (int kk = 0; kk < 4; ++kk) bfrag[kk] = *(const short8*)(srow + kk * 32);
        f32x4 accv[4];
#pragma unroll
        for (int t = 0; t < 4; ++t) { f32x4 z = {0.f, 0.f, 0.f, 0.f}; accv[t] = z; }
#pragma unroll
        for (int t = 0; t < 4; ++t) {
            const int mg = mhalf * 4 + t;
            const unsigned short* arow = &wvs[(mg * 16 + m16) * WVS + q * 8];
#pragma unroll
            for (int kk = 0; kk < 4; ++kk) {
                short8 af = *(const short8*)(arow + kk * 32);
                accv[t] = __builtin_amdgcn_mfma_f32_16x16x32_bf16(af, bfrag[kk], accv[t], 0, 0, 0);
            }
        }
#pragma unroll
        for (int t = 0; t < 4; ++t) {
            const int mg = mhalf * 4 + t;
#pragma unroll
            for (int r = 0; r < 4; ++r) {
                const int c = mg * 16 + q * 4 + r;
                const size_t idx = ((size_t)(b * Cn + c)) * HWn + n;
                out[idx] = fmap[idx] + g * accv[t][r];
            }
        }
    }
}
}  // namespace

extern "C" void kernel_launch(void* const* d_in, const int* in_sizes, int n_in,
                              void* d_out, int out_size, void* d_ws, size_t ws_size,
                              hipStream_t stream) {
    const float* attn  = (const float*)d_in[0];
    const float* fmap  = (const float*)d_in[1];
    const float* Wv    = (const float*)d_in[2];
    const float* gamma = (const float*)d_in[3];
    float* out = (float*)d_out;

    lsa_fused<<<dim3(256), NT, 0, stream>>>(attn, fmap, Wv, gamma, out);
}